// Round 2
// baseline (23922.870 us; speedup 1.0000x reference)
//
#include <hip/hip_runtime.h>

// Problem constants: N=1024, K=32, F=8192, E=64, H1=128, H2=64, T=3

// ---------------------------------------------------------------------------
// K1: G0 = X @ W_emb (f64 accumulation), feat0 = relu(G0 + b_emb), out=feat0
// ---------------------------------------------------------------------------
__global__ __launch_bounds__(256) void k_embed(
    const float* __restrict__ X, const float* __restrict__ W_emb,
    const float* __restrict__ b_emb,
    float* __restrict__ G0, float* __restrict__ feat0, float* __restrict__ out)
{
  const int t = threadIdx.x;
  const int j = t & 63;
  const int node = (blockIdx.x << 2) + (t >> 6);
  const float* __restrict__ xr = X + (size_t)node * 8192;
  const float* __restrict__ wp = W_emb + j;
  double a0 = 0.0, a1 = 0.0, a2 = 0.0, a3 = 0.0;
  for (int f = 0; f < 8192; f += 4) {
    float x0 = xr[f + 0], x1 = xr[f + 1], x2 = xr[f + 2], x3 = xr[f + 3];
    a0 = fma((double)x0, (double)wp[(f + 0) << 6], a0);
    a1 = fma((double)x1, (double)wp[(f + 1) << 6], a1);
    a2 = fma((double)x2, (double)wp[(f + 2) << 6], a2);
    a3 = fma((double)x3, (double)wp[(f + 3) << 6], a3);
  }
  float g = (float)((a0 + a1) + (a2 + a3));
  const int o = node * 64 + j;
  G0[o] = g;
  float f0 = fmaxf(g + b_emb[j], 0.0f);
  feat0[o] = f0;
  out[o] = f0;
}

// ---------------------------------------------------------------------------
// K2: Y0 = feat0 @ W1b (W1 rows 64..127); Y = Y0 working copy
// ---------------------------------------------------------------------------
__global__ __launch_bounds__(128) void k_y0(
    const float* __restrict__ feat0, const float* __restrict__ W1,
    float* __restrict__ Y0, float* __restrict__ Y)
{
  const int c = threadIdx.x;
  const int i = blockIdx.x;
  const float* __restrict__ fr = feat0 + i * 64;
  float acc = 0.0f;
  #pragma unroll 8
  for (int e = 0; e < 64; ++e)
    acc = fmaf(fr[e], W1[(64 + e) * 128 + c], acc);
  Y0[i * 128 + c] = acc;
  Y[i * 128 + c] = acc;
}

// ---------------------------------------------------------------------------
// K3: serial chain. One 512-thread block. All step-loop loads come from LDS;
// W2 pinned in VGPRs (volatile one-time load). 3 barriers/step.
// ---------------------------------------------------------------------------
__global__ __launch_bounds__(512, 2) void k_serial(
    const int* __restrict__ neighbors,
    const float* __restrict__ W1, const float* __restrict__ b1,
    float* W2,   // NOT const/restrict: loaded once via volatile to pin in VGPRs
    const float* __restrict__ b2,
    const float* __restrict__ W_lk, const float* __restrict__ b_lk,
    const float* __restrict__ W_act, const float* __restrict__ b_act,
    const float* __restrict__ b_emb,
    const float* __restrict__ G0, const float* __restrict__ feat0,
    const float* __restrict__ Y0, float* __restrict__ Y,
    float* __restrict__ feature)   // == d_out
{
  __shared__ float W1s[128 * 128];        // 64 KB
  __shared__ float Yl[32][128];           // 16 KB  current feature@W1b for neighbors
  __shared__ float Y0l[32][128];          // 16 KB  feat0@W1b for neighbors
  __shared__ float G0l[32][64];           // 8 KB   G0 rows for neighbors
  __shared__ float f0l[32][64];           // 8 KB   feat0 rows for neighbors
  __shared__ float h1s[33][128];          // 16.5 KB
  __shared__ float h2s[33][64];           // 8.25 KB
  __shared__ float a1s[128];
  __shared__ float fis[64], gis[64], sumg[64];
  __shared__ float b1s[128], b2s[64], bembs[64], wlks[64], wacts[128];
  __shared__ float lks[33];
  __shared__ int idxs[32];
  __shared__ int s_u, s_upd, s_utc, s_done;
  __shared__ unsigned s_valid, s_mu, s_mi;
  __shared__ float s_cntf;

  const int t = threadIdx.x;
  const int lane = t & 63;
  const int wave = t >> 6;

  // ---- one-time staging ----
  #pragma unroll
  for (int m = 0; m < 8; ++m) {
    int i4 = (m * 512 + t) << 2;
    *(float4*)&W1s[i4] = *(const float4*)&W1[i4];
  }
  if (t < 128) { b1s[t] = b1[t]; wacts[t] = W_act[t]; }
  if (t < 64) { b2s[t] = b2[t]; bembs[t] = b_emb[t]; wlks[t] = W_lk[t]; }
  const float blkv = b_lk[0];
  const float ba0 = b_act[0];
  const float ba1 = b_act[1];
  // W2 column `lane` pinned in VGPRs; volatile forbids rematerialization.
  float w2r[128];
  {
    const volatile float* W2v = W2;
    #pragma unroll
    for (int c = 0; c < 128; ++c) w2r[c] = W2v[c * 64 + lane];
  }
  __syncthreads();

  for (int i = 0; i < 1024; ++i) {
    // ---- phase0: per-node prefetch (all from L2, bulk parallel) ----
    #pragma unroll
    for (int p = 0; p < 2; ++p) {
      int k = (t >> 5) + (p << 4);          // 0..31
      int c4 = (t & 31) << 2;
      int v = neighbors[i * 32 + k];
      *(float4*)&Yl[k][c4]  = *(const float4*)&Y[v * 128 + c4];
      *(float4*)&Y0l[k][c4] = *(const float4*)&Y0[v * 128 + c4];
    }
    {
      int k = t >> 4;                       // 0..31
      int c4 = (t & 15) << 2;
      int v = neighbors[i * 32 + k];
      *(float4*)&G0l[k][c4] = *(const float4*)&G0[v * 64 + c4];
      *(float4*)&f0l[k][c4] = *(const float4*)&feat0[v * 64 + c4];
    }
    if (t < 64) { fis[t] = feature[i * 64 + t]; gis[t] = G0[i * 64 + t]; sumg[t] = 0.f; }
    if (t < 32) idxs[t] = neighbors[i * 32 + t];
    if (t == 0) { s_valid = 0xFFFFFFFFu; s_cntf = 0.f; s_done = 0; }
    __syncthreads();
    // ---- a1 = fi @ W1a + b1 (from LDS) ----
    if (t < 128) {
      float aa0 = b1s[t], aa1 = 0.0f;
      #pragma unroll 8
      for (int e = 0; e < 64; e += 2) {
        aa0 = fmaf(fis[e],     W1s[e * 128 + t],       aa0);
        aa1 = fmaf(fis[e + 1], W1s[(e + 1) * 128 + t], aa1);
      }
      a1s[t] = aa0 + aa1;
    }
    __syncthreads();

    for (int st = 0; st < 3; ++st) {
      // ---- B12 fused: wave w owns rows {w, w+8, w+16, w+24 (,32 for w0)} ----
      for (int k = wave; k < 33; k += 8) {
        // B1: produce h1 row (each lane covers c = 2*lane, 2*lane+1)
        float2 av = *(const float2*)&a1s[lane << 1];
        float hx = av.x, hy = av.y;
        if (k < 32) {
          int v = idxs[k];
          if (v > 0) {
            float2 yv = *(const float2*)&Yl[k][lane << 1];
            hx += yv.x; hy += yv.y;
          }
        }
        hx = fmaxf(hx, 0.f); hy = fmaxf(hy, 0.f);
        float2 hw = {hx, hy};
        *(float2*)&h1s[k][lane << 1] = hw;
        // B2: h2[k][lane] = relu(h1[k] . W2[:,lane] + b2); lk via shuffle reduce
        float2 A = {b2s[lane], 0.f};
        float2 B = {0.f, 0.f};
        #pragma unroll
        for (int m = 0; m < 32; ++m) {
          float4 hv = *(const float4*)&h1s[k][m << 2];   // wave-uniform broadcast
          A.x = fmaf(hv.x, w2r[(m << 2) + 0], A.x);
          A.y = fmaf(hv.y, w2r[(m << 2) + 1], A.y);
          B.x = fmaf(hv.z, w2r[(m << 2) + 2], B.x);
          B.y = fmaf(hv.w, w2r[(m << 2) + 3], B.y);
        }
        float h2v = fmaxf((A.x + A.y) + (B.x + B.y), 0.f);
        h2s[k][lane] = h2v;
        float p = h2v * wlks[lane];
        #pragma unroll
        for (int off = 32; off; off >>= 1) p += __shfl_down(p, off);
        if (lane == 0) lks[k] = p + blkv;
      }
      __syncthreads();
      // ---- P4+D fused (wave 0 only) ----
      if (wave == 0) {
        const unsigned vm = s_valid;
        const float cnt_old = s_cntf;
        const int done_old = s_done;
        float v = -__builtin_inff();
        int ki = 64;
        if (lane < 33) {
          bool m = (lane == 32) || ((vm >> lane) & 1u);
          v = m ? lks[lane] : -__builtin_inff();
          ki = lane;
        }
        #pragma unroll
        for (int off = 32; off; off >>= 1) {
          float ov = __shfl_down(v, off);
          int   oi = __shfl_down(ki, off);
          if (ov > v || (ov == v && oi < ki)) { v = ov; ki = oi; }
        }
        const int ut = __shfl(ki, 0);
        const int utc = ut < 31 ? ut : 31;
        // action argmax on hidden[utc]
        float h = h2s[utc][lane];
        float p0 = h * wacts[(lane << 1) + 0];
        float p1 = h * wacts[(lane << 1) + 1];
        #pragma unroll
        for (int off = 32; off; off >>= 1) {
          p0 += __shfl_down(p0, off);
          p1 += __shfl_down(p1, off);
        }
        int at1 = 0;
        if (lane == 0) at1 = ((p1 + ba1) > (p0 + ba0)) ? 1 : 0;
        at1 = __shfl(at1, 0);
        const int newdone = done_old | (ut == 32);
        const int upd = newdone ? 0 : 1;
        const float take = at1 ? 1.0f : 0.0f;
        const float denom = cnt_old + take + 1.0f;
        const int u = idxs[utc];
        unsigned long long bu = __ballot(lane < 32 && idxs[lane] == u);
        unsigned long long bi = __ballot(lane < 32 && idxs[lane] == i);
        if (lane == 0) {
          s_u = u; s_upd = upd; s_utc = utc; s_done = newdone;
          s_mu = (unsigned)bu; s_mi = (unsigned)bi;
          if (upd) { s_valid = vm & ~(1u << utc); s_cntf = cnt_old + take; }
        }
        if (upd) {
          // D: state update in G-space, all from LDS
          const float gu = G0l[utc][lane];
          const float ns = sumg[lane] + take * gu;
          const float hv = (ns + gis[lane]) / denom;
          const float nfi = fmaxf(hv + bembs[lane], 0.0f);
          sumg[lane] = ns;
          const float f0u = f0l[utc][lane];
          feature[i * 64 + lane] = nfi;            // then feature[u] wins if u==i
          feature[u * 64 + lane] = f0u;
          fis[lane] = (u == i) ? f0u : nfi;
        }
      }
      __syncthreads();
      if (!s_upd) break;
      // ---- E: Y[i]=fi_new@W1b, Y[u]=Y0[u], a1 for next step, Yl patches ----
      if (t < 128) {
        const int u = s_u, utc = s_utc;
        const int c = t;
        float acc0 = 0.f, acc1 = 0.f;
        float aa0 = b1s[c], aa1 = 0.f;
        #pragma unroll 4
        for (int e = 0; e < 64; e += 2) {
          float f0v = fis[e], f1v = fis[e + 1];
          acc0 = fmaf(f0v, W1s[(64 + e) * 128 + c], acc0);
          acc1 = fmaf(f1v, W1s[(64 + e + 1) * 128 + c], acc1);
          aa0  = fmaf(f0v, W1s[e * 128 + c], aa0);
          aa1  = fmaf(f1v, W1s[(e + 1) * 128 + c], aa1);
        }
        const float yi = acc0 + acc1;
        const float yu = Y0l[utc][c];
        Y[i * 128 + c] = yi;                       // then Y[u] wins if u==i
        Y[u * 128 + c] = yu;
        a1s[c] = aa0 + aa1;
        // patch LDS neighbor cache: slots holding u -> Y0 row; slots holding i -> yi
        const unsigned mu = s_mu;
        for (unsigned m = mu; m; m &= m - 1) {
          int k = __ffs(m) - 1;
          Yl[k][c] = Y0l[k][c];
        }
        for (unsigned m = s_mi & ~mu; m; m &= m - 1) {
          int k = __ffs(m) - 1;
          Yl[k][c] = yi;
        }
      }
      __syncthreads();
    }
  }
}

// ---------------------------------------------------------------------------
extern "C" void kernel_launch(void* const* d_in, const int* in_sizes, int n_in,
                              void* d_out, int out_size, void* d_ws, size_t ws_size,
                              hipStream_t stream) {
  const float* X     = (const float*)d_in[0];
  const int*   nbr   = (const int*)  d_in[1];
  const float* W_emb = (const float*)d_in[2];
  const float* b_emb = (const float*)d_in[3];
  const float* W1    = (const float*)d_in[4];
  const float* b1    = (const float*)d_in[5];
  float*       W2    = (float*)      d_in[6];
  const float* b2    = (const float*)d_in[7];
  const float* W_lk  = (const float*)d_in[8];
  const float* b_lk  = (const float*)d_in[9];
  const float* W_act = (const float*)d_in[10];
  const float* b_act = (const float*)d_in[11];
  float* out = (float*)d_out;
  float* ws  = (float*)d_ws;
  float* G0    = ws;             // [1024*64]
  float* feat0 = ws + 65536;     // [1024*64]
  float* Y0    = ws + 131072;    // [1024*128]
  float* Y     = ws + 262144;    // [1024*128]

  hipLaunchKernelGGL(k_embed, dim3(256), dim3(256), 0, stream,
                     X, W_emb, b_emb, G0, feat0, out);
  hipLaunchKernelGGL(k_y0, dim3(1024), dim3(128), 0, stream,
                     feat0, W1, Y0, Y);
  hipLaunchKernelGGL(k_serial, dim3(1), dim3(512), 0, stream,
                     nbr, W1, b1, W2, b2, W_lk, b_lk, W_act, b_act, b_emb,
                     G0, feat0, Y0, Y, out);
}